// Round 4
// baseline (101.945 us; speedup 1.0000x reference)
//
#include <hip/hip_runtime.h>

// Problem constants (from reference): B=8, H=1024, NIN=256, C=128, E=16
#define B_    8
#define H_    1024
#define NIN_  256
#define C_    128
#define E_    16

// clang native 4-float vector — required by __builtin_nontemporal_load/store
typedef float f4_t __attribute__((ext_vector_type(4)));

// ---------------------------------------------------------------------------
// Kernel 1: compute s_t[b,h] = sum_n vt[n] * x[b,n,h]  (and s_p with vp)
//   vt[n] = sum_c Wcat[E+c]   * Wt[c*NIN+n]
//   vp[n] = sum_c Wcat[E+C+c] * Wp[c*NIN+n]
// ---------------------------------------------------------------------------
__global__ __launch_bounds__(256) void compute_s_kernel(
    const float* __restrict__ x,     // (B, NIN, H)
    const float* __restrict__ Wt,    // (C, NIN)
    const float* __restrict__ Wp,    // (C, NIN)
    const float* __restrict__ Wcat,  // (E + 2C,)
    float* __restrict__ s_t,         // (B, H)
    float* __restrict__ s_p)         // (B, H)
{
    __shared__ float vt[NIN_];
    __shared__ float vp[NIN_];
    __shared__ float red_t[4][64];
    __shared__ float red_p[4][64];

    const int tid = threadIdx.x;

    // Phase A: fold Wcat into Wt/Wp columns. tid == n (NIN == blockDim).
    {
        float at = 0.f, ap = 0.f;
        #pragma unroll 4
        for (int c = 0; c < C_; ++c) {
            at += Wcat[E_ + c]      * Wt[c * NIN_ + tid];
            ap += Wcat[E_ + C_ + c] * Wp[c * NIN_ + tid];
        }
        vt[tid] = at;
        vp[tid] = ap;
    }
    __syncthreads();

    // Phase B
    const int b  = blockIdx.x >> 4;            // H/64 = 16 chunks per b
    const int h0 = (blockIdx.x & 15) << 6;     // *64
    const int hl = tid & 63;
    const int ng = tid >> 6;                   // 0..3
    const int h  = h0 + hl;

    const float* xb = x + (size_t)b * NIN_ * H_ + h;
    float at = 0.f, ap = 0.f;
    const int n0 = ng << 6;
    #pragma unroll 8
    for (int k = 0; k < 64; ++k) {
        const int n = n0 + k;
        const float xv = xb[(size_t)n * H_];
        at += vt[n] * xv;
        ap += vp[n] * xv;
    }
    red_t[ng][hl] = at;
    red_p[ng][hl] = ap;
    __syncthreads();

    if (ng == 0) {
        const float st = red_t[0][hl] + red_t[1][hl] + red_t[2][hl] + red_t[3][hl];
        const float sp = red_p[0][hl] + red_p[1][hl] + red_p[2][hl] + red_p[3][hl];
        s_t[b * H_ + h] = st;
        s_p[b * H_ + h] = sp;
    }
}

// ---------------------------------------------------------------------------
// Kernel 2: out[b,h,w] = sum_e Wcat[e]*edges[b,e,h,w] + s_t[b,h] + s_p[b,w]
//
// DRAM-locality v2: each block owns a CONTIGUOUS 8192-float4 (128 KB) chunk
// = 32 full h-rows of one b's plane. Per e-plane it issues 16 back-to-back
// wave-load rounds covering 128 KB sequential before switching streams.
// Grid = exactly 256 blocks (1/CU, perfectly balanced); 512 threads.
// Stream fronts chip-wide: 256 x 17 ~ 4.3k (was 17k at R0, 35k at baseline).
// ---------------------------------------------------------------------------
#define T2_   512            // threads
#define R_    16             // rounds: chunk = T2_ * R_ float4 = 128 KB
#define HH4_  (H_ * H_ / 4)  // 262144 float4 per (b,e) plane
#define CPB_  (HH4_ / (T2_ * R_))   // 32 chunks per b-plane

__global__ __launch_bounds__(T2_) void affinity_main_kernel(
    const float* __restrict__ edges,  // (B, E, H, H)
    const float* __restrict__ Wcat,   // first E entries = w_e
    const float* __restrict__ s_t,    // (B, H)
    const float* __restrict__ s_p,    // (B, H)
    float* __restrict__ out)          // (B, H, H) flat
{
    const int tid  = threadIdx.x;          // 0..511
    const int bid  = blockIdx.x;           // 0..255
    const int b    = bid / CPB_;            // 32 chunks per b
    const int rem0 = (bid % CPB_) * (T2_ * R_);  // chunk start in float4 units
    const int h0   = rem0 >> 8;             // first h-row (32 rows per chunk)
    const int hsub = tid >> 8;               // 0 or 1: which half-row-pair
    const int w4   = tid & 255;              // float4 column

    float we[E_];
    #pragma unroll
    for (int e = 0; e < E_; ++e) we[e] = Wcat[e];

    // acc[r] covers float4 index rem0 + r*512 + tid  ->  h = h0 + 2r + hsub
    const f4_t sp = ((const f4_t*)s_p)[b * (H_ / 4) + w4];
    f4_t acc[R_];
    #pragma unroll
    for (int r = 0; r < R_; ++r) {
        const float st = s_t[b * H_ + h0 + 2 * r + hsub];  // wave-uniform
        acc[r] = sp + st;
    }

    const f4_t* ebase = (const f4_t*)edges
                      + (size_t)b * E_ * HH4_ + rem0 + tid;

    #pragma unroll
    for (int e = 0; e < E_; ++e) {
        const f4_t* pe = ebase + (size_t)e * HH4_;
        f4_t ev[R_];
        #pragma unroll
        for (int r = 0; r < R_; ++r)
            ev[r] = __builtin_nontemporal_load(&pe[r * T2_]);
        #pragma unroll
        for (int r = 0; r < R_; ++r)
            acc[r] += we[e] * ev[r];
    }

    f4_t* o = (f4_t*)out + (size_t)b * HH4_ + rem0 + tid;
    #pragma unroll
    for (int r = 0; r < R_; ++r)
        __builtin_nontemporal_store(acc[r], &o[r * T2_]);
}

extern "C" void kernel_launch(void* const* d_in, const int* in_sizes, int n_in,
                              void* d_out, int out_size, void* d_ws, size_t ws_size,
                              hipStream_t stream) {
    // Inputs in setup_inputs() order:
    //   0: adj  (B,H,H)    f32 -- UNUSED by the reference
    //   1: edges(B,E,H,H)  f32
    //   2: x    (B,NIN,H)  f32
    //   3: Wt   (C,NIN)    f32
    //   4: Wp   (C,NIN)    f32
    //   5: Wcat (E+2C,)    f32
    const float* edges = (const float*)d_in[1];
    const float* x     = (const float*)d_in[2];
    const float* Wt    = (const float*)d_in[3];
    const float* Wp    = (const float*)d_in[4];
    const float* Wcat  = (const float*)d_in[5];
    float* out = (float*)d_out;

    float* s_t = (float*)d_ws;            // B*H floats = 32 KB
    float* s_p = s_t + B_ * H_;           // B*H floats = 32 KB

    compute_s_kernel<<<B_ * (H_ / 64), 256, 0, stream>>>(x, Wt, Wp, Wcat, s_t, s_p);

    affinity_main_kernel<<<B_ * CPB_, T2_, 0, stream>>>(edges, Wcat, s_t, s_p, out);
}